// Round 3
// baseline (3463.302 us; speedup 1.0000x reference)
//
// pendulumRNNSA — persistent 2-layer LSTM (B=256,T=512,H=256) + fused MFMA attention.
//
// Round 13 — same geometry, register cap pinned via direct clang attributes:
//  * Rounds 11/12 post-mortem: VGPR_Count stayed 64 under BOTH
//    __launch_bounds__(1024) and __launch_bounds__(1024, 4) — the toolchain
//    resolved occupancy to 8 waves/EU (cap 512/8 = 64) regardless. The ~124
//    VGPR live set (96 of weight fragments) spilled to scratch; L2-latency
//    reloads each K-step explain dur 3260 us / MfmaUtil 5% / unchanged FETCH.
//    Neither round tested the consumers-4 hypothesis.
//  * Change ONE variable: replace __launch_bounds__ with
//    __attribute__((amdgpu_flat_work_group_size(1024,1024),
//                   amdgpu_waves_per_eu(4,4)))
//    => backend VGPR budget = 512/4 = 128. 16 waves x 128 VGPR = 2048 = full
//    CU pool; LDS ~104 KB keeps 1 block/CU. Gating observable: VGPR_Count
//    must read ~120-128. If still 64, abandon 1024-thread geometry (revert to
//    round-10 128x512 next round).
//  * Geometry unchanged: 64 blocks x 1024 threads (16 batch-groups x 4
//    hidden-groups, 16 waves). Consumers per produced h element = 4 =>
//    exchange read demand 2 MB/phase (validated by rounds 11/12 FETCH).
//  * Everything else = round 6/10 verbatim: u32 (hi|lo bf16) exchange @
//    relaxed agent scope (~fp23 recurrence), per-group flag barrier (4 private
//    slots), bounded spins (degrade, never hang), H2out stored after flag
//    post, two-cell software pipeline (cell1 @ t=k, cell2 @ t=k-1).
#include <hip/hip_runtime.h>
#include <hip/hip_bf16.h>

#define HD   256
#define TT   512

typedef unsigned short u16;
typedef unsigned int   u32;
typedef unsigned long long u64;
typedef __attribute__((ext_vector_type(8))) short  short8;
typedef __attribute__((ext_vector_type(4))) float  f32x4;

__device__ __forceinline__ float bf2f(u16 v) { return __uint_as_float(((u32)v) << 16); }
__device__ __forceinline__ u16 f2bf(float f) {
    u32 u = __float_as_uint(f);
    u32 r = u + 0x7fffu + ((u >> 16) & 1u);   // RNE
    return (u16)(r >> 16);
}
__device__ __forceinline__ float sigf(float x)  { return __builtin_amdgcn_rcpf(1.f + __expf(-x)); }
__device__ __forceinline__ float tanhf_(float x){ float e = __expf(-2.f * x);
                                                  return 2.f * __builtin_amdgcn_rcpf(1.f + e) - 1.f; }

__global__ void cvt_bf_kernel(const float* __restrict__ src, u16* __restrict__ dst, int n) {
    int idx = blockIdx.x * 256 + threadIdx.x;
    if (idx < n) dst[idx] = f2bf(src[idx]);
}

__global__ void bias_kernel(const float* __restrict__ a1, const float* __restrict__ b1,
                            const float* __restrict__ a2, const float* __restrict__ b2,
                            float* __restrict__ o1, float* __restrict__ o2) {
    int i = blockIdx.x * 256 + threadIdx.x;
    o1[i] = a1[i] + b1[i];
    o2[i] = a2[i] + b2[i];
}

__device__ __forceinline__ void load_bfrag(const float* __restrict__ W, int row, int kq, short8* bw) {
#pragma unroll
    for (int kk = 0; kk < 8; ++kk) {
        const float* p = W + row * 256 + kk * 32 + kq * 8;
        short8 s;
#pragma unroll
        for (int j = 0; j < 8; ++j) s[j] = (short)f2bf(p[j]);
        bw[kk] = s;
    }
}

__device__ __forceinline__ u64 aload64(const u64* p) {
    return __hip_atomic_load(p, __ATOMIC_RELAXED, __HIP_MEMORY_SCOPE_AGENT);
}
__device__ __forceinline__ void astore32(u32* p, u32 v) {
    __hip_atomic_store(p, v, __ATOMIC_RELAXED, __HIP_MEMORY_SCOPE_AGENT);
}

// flag wait: lanes 0..3 poll the group's 4 slots (relaxed agent loads).
__device__ __forceinline__ void flag_wait(const u32* flags, int gb, u32 target) {
    if (threadIdx.x < 4) {
        const u32* slot = flags + (gb * 4 + (int)threadIdx.x) * 32;
        int sp = 0;
        while (__hip_atomic_load(slot, __ATOMIC_RELAXED, __HIP_MEMORY_SCOPE_AGENT) < target) {
            if (++sp > (1 << 24)) break;
        }
    }
    __syncthreads();
}

// flag post: __syncthreads drains vmcnt(0) (h stores at the coherent point),
// then leader publishes the phase to this block's private slot.
__device__ __forceinline__ void flag_post(u32* flags, int slotidx, u32 val) {
    __syncthreads();
    if (threadIdx.x == 0)
        __hip_atomic_store(flags + slotidx * 32, val, __ATOMIC_RELAXED, __HIP_MEMORY_SCOPE_AGENT);
}

// Hb layout: [parity][256 batch][256 hidden] u32 = (hi bf16) | (lo bf16 << 16).
__global__ __attribute__((amdgpu_flat_work_group_size(1024, 1024), amdgpu_waves_per_eu(4, 4)))
void lstm_persist(
    const float* __restrict__ x,
    const float* __restrict__ Wih1,
    const float* __restrict__ bias1,
    const float* __restrict__ bias2,
    const float* __restrict__ Whh1,
    const float* __restrict__ Wih2,
    const float* __restrict__ Whh2,
    u32* __restrict__ Hb1, u32* __restrict__ Hb2,
    u16* __restrict__ H2out, u32* flags)
{
    __shared__ __align__(16) u16 sh1hi[16 * 264], sh1lo[16 * 264];
    __shared__ __align__(16) u16 sh2hi[16 * 264], sh2lo[16 * 264];
    __shared__ float xs[TT * 16];
    __shared__ float gbuf1[4 * 16 * 68], gbuf2[4 * 16 * 68];
    __shared__ float wihs[256], b1s[256], b2s[256];

    const int tid = threadIdx.x;
    const int blk = blockIdx.x;              // 0..63
    const int gb = blk >> 2, hg = blk & 3;   // 16 batch-groups x 4 hidden-groups
    const int l = tid & 63, wv = tid >> 6;   // 16 waves
    const int g = wv >> 2, cg = wv & 3;      // gate, 16-col group within 64-col slice
    const int nloc = l & 15, kq = l >> 4;
    const int wrow = g * 256 + hg * 64 + cg * 16 + nloc;   // this lane's gate row

    short8 bW1[8], bW2[8], bW3[8];
    load_bfrag(Whh1, wrow, kq, bW1);
    load_bfrag(Wih2, wrow, kq, bW2);
    load_bfrag(Whh2, wrow, kq, bW3);

    for (int idx = tid; idx < 16 * TT; idx += 1024) {
        int b = idx >> 9, t = idx & 511;
        xs[t * 16 + b] = x[(gb * 16 + b) * TT + t];
    }
    if (tid < 256) {
        int rr = (tid >> 6) * 256 + hg * 64 + (tid & 63);   // gate=tid>>6, local=tid&63
        wihs[tid] = Wih1[rr]; b1s[tid] = bias1[rr]; b2s[tid] = bias2[rr];
    }

    // zero own state patches (both parities) — ws is re-poisoned each launch
    const int cb = tid >> 6, ci = tid & 63;                 // 16 batch x 64 hidden = 1024
    const int bg = gb * 16 + cb, ig = hg * 64 + ci;
#pragma unroll
    for (int pp = 0; pp < 2; ++pp) {
        astore32(&Hb1[((pp * 256 + bg) << 8) + ig], 0u);
        astore32(&Hb2[((pp * 256 + bg) << 8) + ig], 0u);
    }
    float c1 = 0.f, c2 = 0.f;

    flag_post(flags, gb * 4 + hg, 1u);   // phase-1: zeroing done

    const int aoff = nloc * 264 + kq * 8;
    const int sb = tid >> 6, scol = (tid & 63) * 4;   // staging: row sb, u32 cols scol..scol+3
    const int sbase = sb * 264 + scol;

    for (int k = 0; k <= TT; ++k) {
        flag_wait(flags, gb, (u32)(k + 1));

        const int rp = k & 1, wp = rp ^ 1;
        // ---- stage h1(k-1), h2(k-2): 4 u32 from each buffer per thread (2x 8B loads each)
        {
            const u32* p1 = Hb1 + ((rp * 256 + gb * 16 + sb) << 8) + scol;
            const u32* p2 = Hb2 + ((rp * 256 + gb * 16 + sb) << 8) + scol;
            u64 t10 = aload64((const u64*)p1);
            u64 t11 = aload64((const u64*)p1 + 1);
            u64 t20 = aload64((const u64*)p2);
            u64 t21 = aload64((const u64*)p2 + 1);
            // unpack hi|lo planes -> one b64 LDS store per plane
            u32 w0 = (u32)t10, w1 = (u32)(t10 >> 32), w2 = (u32)t11, w3 = (u32)(t11 >> 32);
            uint2 vhi, vlo;
            vhi.x = (w0 & 0xffffu) | (w1 << 16);  vhi.y = (w2 & 0xffffu) | (w3 << 16);
            vlo.x = (w0 >> 16) | (w1 & 0xffff0000u);  vlo.y = (w2 >> 16) | (w3 & 0xffff0000u);
            *(uint2*)(sh1hi + sbase) = vhi;
            *(uint2*)(sh1lo + sbase) = vlo;
            w0 = (u32)t20; w1 = (u32)(t20 >> 32); w2 = (u32)t21; w3 = (u32)(t21 >> 32);
            vhi.x = (w0 & 0xffffu) | (w1 << 16);  vhi.y = (w2 & 0xffffu) | (w3 << 16);
            vlo.x = (w0 >> 16) | (w1 & 0xffff0000u);  vlo.y = (w2 >> 16) | (w3 & 0xffff0000u);
            *(uint2*)(sh2hi + sbase) = vhi;
            *(uint2*)(sh2lo + sbase) = vlo;
        }
        __syncthreads();

        f32x4 acc1a = {0,0,0,0}, acc1b = {0,0,0,0};
        f32x4 acc2a = {0,0,0,0}, acc2b = {0,0,0,0};
#pragma unroll
        for (int kk = 0; kk < 8; ++kk) {
            short8 a1h = *(const short8*)(sh1hi + aoff + kk * 32);
            short8 a1l = *(const short8*)(sh1lo + aoff + kk * 32);
            if (k < TT) {
                acc1a = __builtin_amdgcn_mfma_f32_16x16x32_bf16(a1h, bW1[kk], acc1a, 0, 0, 0);
                acc1b = __builtin_amdgcn_mfma_f32_16x16x32_bf16(a1l, bW1[kk], acc1b, 0, 0, 0);
            }
            if (k > 0) {
                acc2a = __builtin_amdgcn_mfma_f32_16x16x32_bf16(a1h, bW2[kk], acc2a, 0, 0, 0);
                acc2b = __builtin_amdgcn_mfma_f32_16x16x32_bf16(a1l, bW2[kk], acc2b, 0, 0, 0);
                short8 a2h = *(const short8*)(sh2hi + aoff + kk * 32);
                short8 a2l = *(const short8*)(sh2lo + aoff + kk * 32);
                acc2a = __builtin_amdgcn_mfma_f32_16x16x32_bf16(a2h, bW3[kk], acc2a, 0, 0, 0);
                acc2b = __builtin_amdgcn_mfma_f32_16x16x32_bf16(a2l, bW3[kk], acc2b, 0, 0, 0);
            }
        }
        // D layout: col n=lane&15 (gate-row local), row m=(lane>>4)*4+r (batch)
#pragma unroll
        for (int r = 0; r < 4; ++r) {
            int m = kq * 4 + r;
            gbuf1[(g * 16 + m) * 68 + cg * 16 + nloc] = acc1a[r] + acc1b[r];
            gbuf2[(g * 16 + m) * 68 + cg * 16 + nloc] = acc2a[r] + acc2b[r];
        }
        __syncthreads();

        u16 hi2 = 0;
        if (k < TT) {   // cell 1, t = k
            float xv = xs[k * 16 + cb];
            float g0 = gbuf1[(0 * 16 + cb) * 68 + ci] + xv * wihs[ci]       + b1s[ci];
            float g1 = gbuf1[(1 * 16 + cb) * 68 + ci] + xv * wihs[64 + ci]  + b1s[64 + ci];
            float g2 = gbuf1[(2 * 16 + cb) * 68 + ci] + xv * wihs[128 + ci] + b1s[128 + ci];
            float g3 = gbuf1[(3 * 16 + cb) * 68 + ci] + xv * wihs[192 + ci] + b1s[192 + ci];
            float ii = sigf(g0), ff = sigf(g1), gg = tanhf_(g2), oo = sigf(g3);
            c1 = ff * c1 + ii * gg;
            float h = oo * tanhf_(c1);
            u16 hi = f2bf(h); u32 word = (u32)hi | ((u32)f2bf(h - bf2f(hi)) << 16);
            astore32(&Hb1[((wp * 256 + bg) << 8) + ig], word);
        }
        if (k > 0) {    // cell 2, t = k-1
            float g0 = gbuf2[(0 * 16 + cb) * 68 + ci] + b2s[ci];
            float g1 = gbuf2[(1 * 16 + cb) * 68 + ci] + b2s[64 + ci];
            float g2 = gbuf2[(2 * 16 + cb) * 68 + ci] + b2s[128 + ci];
            float g3 = gbuf2[(3 * 16 + cb) * 68 + ci] + b2s[192 + ci];
            float ii = sigf(g0), ff = sigf(g1), gg = tanhf_(g2), oo = sigf(g3);
            c2 = ff * c2 + ii * gg;
            float h = oo * tanhf_(c2);
            hi2 = f2bf(h); u32 word = (u32)hi2 | ((u32)f2bf(h - bf2f(hi2)) << 16);
            astore32(&Hb2[((wp * 256 + bg) << 8) + ig], word);
        }
        flag_post(flags, gb * 4 + hg, (u32)(k + 2));
        // HBM store for the attention pass — AFTER the post, off the critical path
        if (k > 0) H2out[(bg * TT + (k - 1)) * 256 + ig] = hi2;
    }
}

// ---- fused attention: per 64-row tile, S1=tanh(H2@Wa1^T+ba1) -> S2=S1@Wa2^T+ba2
//      -> softmax rows -> out = sum_n p*h2*Wo + bo. MFMA for both matmuls.
__global__ __launch_bounds__(256) void attn_fused(
    const u16*  __restrict__ Wa1b, const u16* __restrict__ Wa2b,
    const float* __restrict__ ba1, const float* __restrict__ ba2,
    const float* __restrict__ Wo,  const float* __restrict__ bo,
    const u16*  __restrict__ H2,   float* __restrict__ out)
{
    __shared__ __align__(16) u16 sA[64 * 264];
    __shared__ __align__(16) u16 sP[64 * 264];
    __shared__ float red[64 * 12];
    __shared__ float sb1[256], sb2[256], swo[256];

    const int tid = threadIdx.x;
    const int w = tid >> 6, l = tid & 63;
    const int c = l & 15, q = l >> 4;
    const int row0 = blockIdx.x * 64;

    {
        const int r = tid >> 2, qq = tid & 3;
        const uint4* src = (const uint4*)(H2 + (row0 + r) * 256 + qq * 64);
#pragma unroll
        for (int j = 0; j < 8; ++j) {
            uint4 v = src[j];
            *(uint4*)(sA + r * 264 + qq * 64 + j * 8) = v;
        }
    }
    if (tid < 256) { sb1[tid] = ba1[tid]; sb2[tid] = ba2[tid]; swo[tid] = Wo[tid]; }
    __syncthreads();

    f32x4 acc[4][4];
#pragma unroll
    for (int mi = 0; mi < 4; ++mi)
#pragma unroll
        for (int ni = 0; ni < 4; ++ni) acc[mi][ni] = (f32x4){0,0,0,0};

#pragma unroll
    for (int ni = 0; ni < 4; ++ni) {
        const int row = w * 64 + ni * 16 + c;
        const u16* wp = Wa1b + row * 256 + q * 8;
        short8 bW[8];
#pragma unroll
        for (int kk = 0; kk < 8; ++kk) bW[kk] = *(const short8*)(wp + kk * 32);
#pragma unroll
        for (int kk = 0; kk < 8; ++kk)
#pragma unroll
            for (int mi = 0; mi < 4; ++mi) {
                short8 a = *(const short8*)(sA + (mi * 16 + c) * 264 + q * 8 + kk * 32);
                acc[mi][ni] = __builtin_amdgcn_mfma_f32_16x16x32_bf16(a, bW[kk], acc[mi][ni], 0, 0, 0);
            }
    }
#pragma unroll
    for (int mi = 0; mi < 4; ++mi)
#pragma unroll
        for (int ni = 0; ni < 4; ++ni) {
            const int n = w * 64 + ni * 16 + c;
            const float bj = sb1[n];
#pragma unroll
            for (int r = 0; r < 4; ++r) {
                int m = mi * 16 + q * 4 + r;
                sP[m * 264 + n] = f2bf(tanhf(acc[mi][ni][r] + bj));
            }
        }
    __syncthreads();

#pragma unroll
    for (int mi = 0; mi < 4; ++mi)
#pragma unroll
        for (int ni = 0; ni < 4; ++ni) acc[mi][ni] = (f32x4){0,0,0,0};
#pragma unroll
    for (int ni = 0; ni < 4; ++ni) {
        const int row = w * 64 + ni * 16 + c;
        const u16* wp = Wa2b + row * 256 + q * 8;
        short8 bW[8];
#pragma unroll
        for (int kk = 0; kk < 8; ++kk) bW[kk] = *(const short8*)(wp + kk * 32);
#pragma unroll
        for (int kk = 0; kk < 8; ++kk)
#pragma unroll
            for (int mi = 0; mi < 4; ++mi) {
                short8 a = *(const short8*)(sP + (mi * 16 + c) * 264 + q * 8 + kk * 32);
                acc[mi][ni] = __builtin_amdgcn_mfma_f32_16x16x32_bf16(a, bW[kk], acc[mi][ni], 0, 0, 0);
            }
    }

    float mx[4][4];
#pragma unroll
    for (int mi = 0; mi < 4; ++mi)
#pragma unroll
        for (int r = 0; r < 4; ++r) mx[mi][r] = -1e30f;
#pragma unroll
    for (int mi = 0; mi < 4; ++mi)
#pragma unroll
        for (int ni = 0; ni < 4; ++ni) {
            const float bj = sb2[w * 64 + ni * 16 + c];
#pragma unroll
            for (int r = 0; r < 4; ++r) {
                float s = acc[mi][ni][r] + bj;
                acc[mi][ni][r] = s;
                mx[mi][r] = fmaxf(mx[mi][r], s);
            }
        }
#pragma unroll
    for (int off = 1; off < 16; off <<= 1)
#pragma unroll
        for (int mi = 0; mi < 4; ++mi)
#pragma unroll
            for (int r = 0; r < 4; ++r) mx[mi][r] = fmaxf(mx[mi][r], __shfl_xor(mx[mi][r], off));
    if (c == 0)
#pragma unroll
        for (int mi = 0; mi < 4; ++mi)
#pragma unroll
            for (int r = 0; r < 4; ++r) red[(mi * 16 + q * 4 + r) * 12 + w] = mx[mi][r];
    __syncthreads();
#pragma unroll
    for (int mi = 0; mi < 4; ++mi)
#pragma unroll
        for (int r = 0; r < 4; ++r) {
            const float* rp = red + (mi * 16 + q * 4 + r) * 12;
            mx[mi][r] = fmaxf(fmaxf(rp[0], rp[1]), fmaxf(rp[2], rp[3]));
        }
    float suml[4][4], sumw[4][4];
#pragma unroll
    for (int mi = 0; mi < 4; ++mi)
#pragma unroll
        for (int r = 0; r < 4; ++r) { suml[mi][r] = 0.f; sumw[mi][r] = 0.f; }
#pragma unroll
    for (int mi = 0; mi < 4; ++mi)
#pragma unroll
        for (int ni = 0; ni < 4; ++ni) {
            const int n = w * 64 + ni * 16 + c;
            const float wov = swo[n];
#pragma unroll
            for (int r = 0; r < 4; ++r) {
                int m = mi * 16 + q * 4 + r;
                float e = __expf(acc[mi][ni][r] - mx[mi][r]);
                suml[mi][r] += e;
                sumw[mi][r] += e * bf2f(sA[m * 264 + n]) * wov;
            }
        }
#pragma unroll
    for (int off = 1; off < 16; off <<= 1)
#pragma unroll
        for (int mi = 0; mi < 4; ++mi)
#pragma unroll
            for (int r = 0; r < 4; ++r) {
                suml[mi][r] += __shfl_xor(suml[mi][r], off);
                sumw[mi][r] += __shfl_xor(sumw[mi][r], off);
            }
    __syncthreads();
    if (c == 0)
#pragma unroll
        for (int mi = 0; mi < 4; ++mi)
#pragma unroll
            for (int r = 0; r < 4; ++r) {
                int m = mi * 16 + q * 4 + r;
                red[m * 12 + 4 + w] = suml[mi][r];
                red[m * 12 + 8 + w] = sumw[mi][r];
            }
    __syncthreads();
    if (tid < 64) {
        const float* rp = red + tid * 12;
        float lsum = rp[4] + rp[5] + rp[6] + rp[7];
        float wsum = rp[8] + rp[9] + rp[10] + rp[11];
        out[row0 + tid] = wsum / lsum + bo[0];
    }
}

extern "C" void kernel_launch(void* const* d_in, const int* in_sizes, int n_in,
                              void* d_out, int out_size, void* d_ws, size_t ws_size,
                              hipStream_t stream) {
    const float* x    = (const float*)d_in[0];
    const float* Wih1 = (const float*)d_in[1];
    const float* bih1 = (const float*)d_in[2];
    const float* Whh1 = (const float*)d_in[3];
    const float* bhh1 = (const float*)d_in[4];
    const float* Wih2 = (const float*)d_in[5];
    const float* bih2 = (const float*)d_in[6];
    const float* Whh2 = (const float*)d_in[7];
    const float* bhh2 = (const float*)d_in[8];
    const float* Wa1  = (const float*)d_in[9];
    const float* ba1  = (const float*)d_in[10];
    const float* Wa2  = (const float*)d_in[11];
    const float* ba2  = (const float*)d_in[12];
    const float* Wo   = (const float*)d_in[13];
    const float* bo   = (const float*)d_in[14];

    char* ws = (char*)d_ws;
    u16*   Wa1b  = (u16*)(ws + 0);                  // 128 KB
    u16*   Wa2b  = (u16*)(ws + 131072);             // 128 KB
    float* bias1 = (float*)(ws + 262144);           // 4 KB
    float* bias2 = (float*)(ws + 266240);           // 4 KB
    u32*   flags = (u32*)(ws + 270336);             // 16 KB (64 x 128B slots used)
    u32*   Hb1   = (u32*)(ws + 524288);             // 512 KB [2][256][256] u32
    u32*   Hb2   = (u32*)(ws + 1048576);            // 512 KB
    u16*   H2    = (u16*)(ws + 2097152);            // 64 MB
    float* out   = (float*)d_out;

    (void)hipMemsetAsync(flags, 0, 16384, stream);
    bias_kernel<<<4, 256, 0, stream>>>(bih1, bhh1, bih2, bhh2, bias1, bias2);
    cvt_bf_kernel<<<256, 256, 0, stream>>>(Wa1, Wa1b, 65536);
    cvt_bf_kernel<<<256, 256, 0, stream>>>(Wa2, Wa2b, 65536);

    lstm_persist<<<64, 1024, 0, stream>>>(x, Wih1, bias1, bias2,
                                          Whh1, Wih2, Whh2, Hb1, Hb2, H2, flags);
    attn_fused<<<2048, 256, 0, stream>>>(Wa1b, Wa2b, ba1, ba2, Wo, bo, H2, out);
}

// Round 4
// 2007.537 us; speedup vs baseline: 1.7251x; 1.7251x over previous
//
// pendulumRNNSA — persistent 2-layer LSTM (B=256,T=512,H=256) + fused MFMA attention.
//
// Round 14 — revert to the proven round-10 base (128x512, VGPR 124, 2047us),
// add ONE variable: XCD-local batch-group placement.
//  * Rounds 11-13 post-mortem: 1024-thread geometry pinned at VGPR_Count=64
//    under __launch_bounds__(1024), (1024,4), AND amdgpu_waves_per_eu(4,4) —
//    weight fragments spilled, dur 3.3ms, consumers-4 hypothesis never tested.
//    Geometry abandoned per the pre-committed exit.
//  * Round-10 model refined: hbm_bytes/dur = 1.45GB/2045us = 710 GB/s —
//    phase time IS the HBM-missed exchange traffic. All exchange is WITHIN a
//    batch-group (its 8 hidden-group blocks are the only producers AND
//    consumers of its 128KB h-state). Old mapping gb=blk>>3,hg=blk&7 +
//    round-robin dispatch (XCD = blk%8, m09) spreads those 8 blocks across 8
//    XCDs => ~50% of exchange demand misses to HBM (2.12MB/phase fetched).
//  * Change: gb = (blk&7) + ((blk>>6)<<3), hg = (blk>>3)&7 — all 8 blocks of
//    batch-group gb land on XCD gb&7. Stores stay dirty in that XCD's L2; all
//    8 readers hit local L2. Working set 2 groups x 128KB << 4MB L2. Agent-
//    scope atomics stay correct under ANY placement (heuristic only; if the
//    %8 mapping is wrong we degrade to round-10 perf, not to wrong answers).
//  * Everything else = round 10 verbatim: u32 (hi|lo bf16) exchange @ relaxed
//    agent scope, per-group flag barrier (8 private slots), bounded spins,
//    H2out stored after flag post, 1 state/thread cell update, LDS ~86KB.
#include <hip/hip_runtime.h>
#include <hip/hip_bf16.h>

#define HD   256
#define TT   512

typedef unsigned short u16;
typedef unsigned int   u32;
typedef unsigned long long u64;
typedef __attribute__((ext_vector_type(8))) short  short8;
typedef __attribute__((ext_vector_type(4))) float  f32x4;

__device__ __forceinline__ float bf2f(u16 v) { return __uint_as_float(((u32)v) << 16); }
__device__ __forceinline__ u16 f2bf(float f) {
    u32 u = __float_as_uint(f);
    u32 r = u + 0x7fffu + ((u >> 16) & 1u);   // RNE
    return (u16)(r >> 16);
}
__device__ __forceinline__ float sigf(float x)  { return __builtin_amdgcn_rcpf(1.f + __expf(-x)); }
__device__ __forceinline__ float tanhf_(float x){ float e = __expf(-2.f * x);
                                                  return 2.f * __builtin_amdgcn_rcpf(1.f + e) - 1.f; }

__global__ void cvt_bf_kernel(const float* __restrict__ src, u16* __restrict__ dst, int n) {
    int idx = blockIdx.x * 256 + threadIdx.x;
    if (idx < n) dst[idx] = f2bf(src[idx]);
}

__global__ void bias_kernel(const float* __restrict__ a1, const float* __restrict__ b1,
                            const float* __restrict__ a2, const float* __restrict__ b2,
                            float* __restrict__ o1, float* __restrict__ o2) {
    int i = blockIdx.x * 256 + threadIdx.x;
    o1[i] = a1[i] + b1[i];
    o2[i] = a2[i] + b2[i];
}

__device__ __forceinline__ void load_bfrag(const float* __restrict__ W, int row, int kq, short8* bw) {
#pragma unroll
    for (int kk = 0; kk < 8; ++kk) {
        const float* p = W + row * 256 + kk * 32 + kq * 8;
        short8 s;
#pragma unroll
        for (int j = 0; j < 8; ++j) s[j] = (short)f2bf(p[j]);
        bw[kk] = s;
    }
}

__device__ __forceinline__ u64 aload64(const u64* p) {
    return __hip_atomic_load(p, __ATOMIC_RELAXED, __HIP_MEMORY_SCOPE_AGENT);
}
__device__ __forceinline__ void astore32(u32* p, u32 v) {
    __hip_atomic_store(p, v, __ATOMIC_RELAXED, __HIP_MEMORY_SCOPE_AGENT);
}

// flag wait: lanes 0..7 poll the group's 8 slots (relaxed agent loads).
__device__ __forceinline__ void flag_wait(const u32* flags, int gb, u32 target) {
    if (threadIdx.x < 8) {
        const u32* slot = flags + (gb * 8 + (int)threadIdx.x) * 32;
        int sp = 0;
        while (__hip_atomic_load(slot, __ATOMIC_RELAXED, __HIP_MEMORY_SCOPE_AGENT) < target) {
            if (++sp > (1 << 24)) break;
        }
    }
    __syncthreads();
}

// flag post: __syncthreads drains vmcnt(0) (h stores at the coherent point),
// then leader publishes the phase to this block's private slot.
__device__ __forceinline__ void flag_post(u32* flags, int slotidx, u32 val) {
    __syncthreads();
    if (threadIdx.x == 0)
        __hip_atomic_store(flags + slotidx * 32, val, __ATOMIC_RELAXED, __HIP_MEMORY_SCOPE_AGENT);
}

// Hb layout: [parity][256 batch][256 hidden] u32 = (hi bf16) | (lo bf16 << 16).
__global__ __launch_bounds__(512) void lstm_persist(
    const float* __restrict__ x,
    const float* __restrict__ Wih1,
    const float* __restrict__ bias1,
    const float* __restrict__ bias2,
    const float* __restrict__ Whh1,
    const float* __restrict__ Wih2,
    const float* __restrict__ Whh2,
    u32* __restrict__ Hb1, u32* __restrict__ Hb2,
    u16* __restrict__ H2out, u32* flags)
{
    __shared__ __align__(16) u16 sh1hi[16 * 264], sh1lo[16 * 264];
    __shared__ __align__(16) u16 sh2hi[16 * 264], sh2lo[16 * 264];
    __shared__ float xs[TT * 16];
    __shared__ float gbuf1[4 * 16 * 36], gbuf2[4 * 16 * 36];
    __shared__ float wihs[128], b1s[128], b2s[128];

    const int tid = threadIdx.x;
    const int blk = blockIdx.x;              // 0..127
    // XCD-local placement: dispatch round-robins XCD = blk % 8 (m09). Putting
    // gb ≡ blk (mod 8) lands all 8 hidden-groups of a batch-group on ONE XCD,
    // so the h exchange stays in that XCD's 4MB L2.
    const int gb = (blk & 7) + ((blk >> 6) << 3);   // 16 batch-groups
    const int hg = (blk >> 3) & 7;                  // 8 hidden-groups
    const int l = tid & 63, wv = tid >> 6;   // 8 waves
    const int g = wv >> 1, hh = wv & 1;      // gate, hidden-half
    const int nloc = l & 15, kq = l >> 4;
    const int wrow = g * 256 + hg * 32 + hh * 16 + nloc;   // this lane's gate row

    short8 bW1[8], bW2[8], bW3[8];
    load_bfrag(Whh1, wrow, kq, bW1);
    load_bfrag(Wih2, wrow, kq, bW2);
    load_bfrag(Whh2, wrow, kq, bW3);

    for (int idx = tid; idx < 16 * TT; idx += 512) {
        int b = idx >> 9, t = idx & 511;
        xs[t * 16 + b] = x[(gb * 16 + b) * TT + t];
    }
    if (tid < 128) {
        int rr = (tid >> 5) * 256 + hg * 32 + (tid & 31);   // gate=tid>>5, local=tid&31
        wihs[tid] = Wih1[rr]; b1s[tid] = bias1[rr]; b2s[tid] = bias2[rr];
    }

    // zero own state patches (both parities) — ws is re-poisoned each launch
    const int cb = tid >> 5, ci = tid & 31;                 // 16 batch x 32 hidden = 512
    const int bg = gb * 16 + cb, ig = hg * 32 + ci;
#pragma unroll
    for (int pp = 0; pp < 2; ++pp) {
        astore32(&Hb1[((pp * 256 + bg) << 8) + ig], 0u);
        astore32(&Hb2[((pp * 256 + bg) << 8) + ig], 0u);
    }
    float c1 = 0.f, c2 = 0.f;

    flag_post(flags, gb * 8 + hg, 1u);   // phase-1: zeroing done

    const int aoff = nloc * 264 + kq * 8;
    const int sb = tid >> 5, scol = (tid & 31) * 8;   // staging: row sb, cols scol..scol+7
    const int sbase = sb * 264 + scol;

    for (int k = 0; k <= TT; ++k) {
        flag_wait(flags, gb, (u32)(k + 1));

        const int rp = k & 1, wp = rp ^ 1;
        // ---- stage h1(k-1), h2(k-2): 8 u32 from each buffer per thread (4x 8B loads)
        {
            const u32* p1 = Hb1 + ((rp * 256 + gb * 16 + sb) << 8) + scol;
            const u32* p2 = Hb2 + ((rp * 256 + gb * 16 + sb) << 8) + scol;
            u32 w1v[8], w2v[8];
#pragma unroll
            for (int j = 0; j < 4; ++j) {
                u64 t = aload64((const u64*)p1 + j);
                w1v[2 * j] = (u32)t; w1v[2 * j + 1] = (u32)(t >> 32);
            }
#pragma unroll
            for (int j = 0; j < 4; ++j) {
                u64 t = aload64((const u64*)p2 + j);
                w2v[2 * j] = (u32)t; w2v[2 * j + 1] = (u32)(t >> 32);
            }
            // unpack hi|lo planes -> one b128 LDS store per plane
            u32 h1h[4], h1l[4], h2h[4], h2l[4];
#pragma unroll
            for (int i = 0; i < 4; ++i) {
                u32 a = w1v[2 * i], b = w1v[2 * i + 1];
                h1h[i] = (a & 0xffffu) | (b << 16);
                h1l[i] = (a >> 16) | (b & 0xffff0000u);
                a = w2v[2 * i]; b = w2v[2 * i + 1];
                h2h[i] = (a & 0xffffu) | (b << 16);
                h2l[i] = (a >> 16) | (b & 0xffff0000u);
            }
            *(uint4*)(sh1hi + sbase) = *(uint4*)(h1h);
            *(uint4*)(sh1lo + sbase) = *(uint4*)(h1l);
            *(uint4*)(sh2hi + sbase) = *(uint4*)(h2h);
            *(uint4*)(sh2lo + sbase) = *(uint4*)(h2l);
        }
        __syncthreads();

        f32x4 acc1a = {0,0,0,0}, acc1b = {0,0,0,0};
        f32x4 acc2a = {0,0,0,0}, acc2b = {0,0,0,0};
#pragma unroll
        for (int kk = 0; kk < 8; ++kk) {
            short8 a1h = *(const short8*)(sh1hi + aoff + kk * 32);
            short8 a1l = *(const short8*)(sh1lo + aoff + kk * 32);
            if (k < TT) {
                acc1a = __builtin_amdgcn_mfma_f32_16x16x32_bf16(a1h, bW1[kk], acc1a, 0, 0, 0);
                acc1b = __builtin_amdgcn_mfma_f32_16x16x32_bf16(a1l, bW1[kk], acc1b, 0, 0, 0);
            }
            if (k > 0) {
                acc2a = __builtin_amdgcn_mfma_f32_16x16x32_bf16(a1h, bW2[kk], acc2a, 0, 0, 0);
                acc2b = __builtin_amdgcn_mfma_f32_16x16x32_bf16(a1l, bW2[kk], acc2b, 0, 0, 0);
                short8 a2h = *(const short8*)(sh2hi + aoff + kk * 32);
                short8 a2l = *(const short8*)(sh2lo + aoff + kk * 32);
                acc2a = __builtin_amdgcn_mfma_f32_16x16x32_bf16(a2h, bW3[kk], acc2a, 0, 0, 0);
                acc2b = __builtin_amdgcn_mfma_f32_16x16x32_bf16(a2l, bW3[kk], acc2b, 0, 0, 0);
            }
        }
        // D layout: col n=lane&15 (gate-row local), row m=(lane>>4)*4+r (batch)
#pragma unroll
        for (int r = 0; r < 4; ++r) {
            int m = (l >> 4) * 4 + r;
            gbuf1[(g * 16 + m) * 36 + hh * 16 + nloc] = acc1a[r] + acc1b[r];
            gbuf2[(g * 16 + m) * 36 + hh * 16 + nloc] = acc2a[r] + acc2b[r];
        }
        __syncthreads();

        u16 hi2 = 0;
        if (k < TT) {   // cell 1, t = k
            float xv = xs[k * 16 + cb];
            float g0 = gbuf1[(0 * 16 + cb) * 36 + ci] + xv * wihs[ci]      + b1s[ci];
            float g1 = gbuf1[(1 * 16 + cb) * 36 + ci] + xv * wihs[32 + ci] + b1s[32 + ci];
            float g2 = gbuf1[(2 * 16 + cb) * 36 + ci] + xv * wihs[64 + ci] + b1s[64 + ci];
            float g3 = gbuf1[(3 * 16 + cb) * 36 + ci] + xv * wihs[96 + ci] + b1s[96 + ci];
            float ii = sigf(g0), ff = sigf(g1), gg = tanhf_(g2), oo = sigf(g3);
            c1 = ff * c1 + ii * gg;
            float h = oo * tanhf_(c1);
            u16 hi = f2bf(h); u32 word = (u32)hi | ((u32)f2bf(h - bf2f(hi)) << 16);
            astore32(&Hb1[((wp * 256 + bg) << 8) + ig], word);
        }
        if (k > 0) {    // cell 2, t = k-1
            float g0 = gbuf2[(0 * 16 + cb) * 36 + ci] + b2s[ci];
            float g1 = gbuf2[(1 * 16 + cb) * 36 + ci] + b2s[32 + ci];
            float g2 = gbuf2[(2 * 16 + cb) * 36 + ci] + b2s[64 + ci];
            float g3 = gbuf2[(3 * 16 + cb) * 36 + ci] + b2s[96 + ci];
            float ii = sigf(g0), ff = sigf(g1), gg = tanhf_(g2), oo = sigf(g3);
            c2 = ff * c2 + ii * gg;
            float h = oo * tanhf_(c2);
            hi2 = f2bf(h); u32 word = (u32)hi2 | ((u32)f2bf(h - bf2f(hi2)) << 16);
            astore32(&Hb2[((wp * 256 + bg) << 8) + ig], word);
        }
        flag_post(flags, gb * 8 + hg, (u32)(k + 2));
        // HBM store for the attention pass — AFTER the post, off the critical path
        if (k > 0) H2out[(bg * TT + (k - 1)) * 256 + ig] = hi2;
    }
}

// ---- fused attention: per 64-row tile, S1=tanh(H2@Wa1^T+ba1) -> S2=S1@Wa2^T+ba2
//      -> softmax rows -> out = sum_n p*h2*Wo + bo. MFMA for both matmuls.
__global__ __launch_bounds__(256) void attn_fused(
    const u16*  __restrict__ Wa1b, const u16* __restrict__ Wa2b,
    const float* __restrict__ ba1, const float* __restrict__ ba2,
    const float* __restrict__ Wo,  const float* __restrict__ bo,
    const u16*  __restrict__ H2,   float* __restrict__ out)
{
    __shared__ __align__(16) u16 sA[64 * 264];
    __shared__ __align__(16) u16 sP[64 * 264];
    __shared__ float red[64 * 12];
    __shared__ float sb1[256], sb2[256], swo[256];

    const int tid = threadIdx.x;
    const int w = tid >> 6, l = tid & 63;
    const int c = l & 15, q = l >> 4;
    const int row0 = blockIdx.x * 64;

    {
        const int r = tid >> 2, qq = tid & 3;
        const uint4* src = (const uint4*)(H2 + (row0 + r) * 256 + qq * 64);
#pragma unroll
        for (int j = 0; j < 8; ++j) {
            uint4 v = src[j];
            *(uint4*)(sA + r * 264 + qq * 64 + j * 8) = v;
        }
    }
    if (tid < 256) { sb1[tid] = ba1[tid]; sb2[tid] = ba2[tid]; swo[tid] = Wo[tid]; }
    __syncthreads();

    f32x4 acc[4][4];
#pragma unroll
    for (int mi = 0; mi < 4; ++mi)
#pragma unroll
        for (int ni = 0; ni < 4; ++ni) acc[mi][ni] = (f32x4){0,0,0,0};

#pragma unroll
    for (int ni = 0; ni < 4; ++ni) {
        const int row = w * 64 + ni * 16 + c;
        const u16* wp = Wa1b + row * 256 + q * 8;
        short8 bW[8];
#pragma unroll
        for (int kk = 0; kk < 8; ++kk) bW[kk] = *(const short8*)(wp + kk * 32);
#pragma unroll
        for (int kk = 0; kk < 8; ++kk)
#pragma unroll
            for (int mi = 0; mi < 4; ++mi) {
                short8 a = *(const short8*)(sA + (mi * 16 + c) * 264 + q * 8 + kk * 32);
                acc[mi][ni] = __builtin_amdgcn_mfma_f32_16x16x32_bf16(a, bW[kk], acc[mi][ni], 0, 0, 0);
            }
    }
#pragma unroll
    for (int mi = 0; mi < 4; ++mi)
#pragma unroll
        for (int ni = 0; ni < 4; ++ni) {
            const int n = w * 64 + ni * 16 + c;
            const float bj = sb1[n];
#pragma unroll
            for (int r = 0; r < 4; ++r) {
                int m = mi * 16 + q * 4 + r;
                sP[m * 264 + n] = f2bf(tanhf(acc[mi][ni][r] + bj));
            }
        }
    __syncthreads();

#pragma unroll
    for (int mi = 0; mi < 4; ++mi)
#pragma unroll
        for (int ni = 0; ni < 4; ++ni) acc[mi][ni] = (f32x4){0,0,0,0};
#pragma unroll
    for (int ni = 0; ni < 4; ++ni) {
        const int row = w * 64 + ni * 16 + c;
        const u16* wp = Wa2b + row * 256 + q * 8;
        short8 bW[8];
#pragma unroll
        for (int kk = 0; kk < 8; ++kk) bW[kk] = *(const short8*)(wp + kk * 32);
#pragma unroll
        for (int kk = 0; kk < 8; ++kk)
#pragma unroll
            for (int mi = 0; mi < 4; ++mi) {
                short8 a = *(const short8*)(sP + (mi * 16 + c) * 264 + q * 8 + kk * 32);
                acc[mi][ni] = __builtin_amdgcn_mfma_f32_16x16x32_bf16(a, bW[kk], acc[mi][ni], 0, 0, 0);
            }
    }

    float mx[4][4];
#pragma unroll
    for (int mi = 0; mi < 4; ++mi)
#pragma unroll
        for (int r = 0; r < 4; ++r) mx[mi][r] = -1e30f;
#pragma unroll
    for (int mi = 0; mi < 4; ++mi)
#pragma unroll
        for (int ni = 0; ni < 4; ++ni) {
            const float bj = sb2[w * 64 + ni * 16 + c];
#pragma unroll
            for (int r = 0; r < 4; ++r) {
                float s = acc[mi][ni][r] + bj;
                acc[mi][ni][r] = s;
                mx[mi][r] = fmaxf(mx[mi][r], s);
            }
        }
#pragma unroll
    for (int off = 1; off < 16; off <<= 1)
#pragma unroll
        for (int mi = 0; mi < 4; ++mi)
#pragma unroll
            for (int r = 0; r < 4; ++r) mx[mi][r] = fmaxf(mx[mi][r], __shfl_xor(mx[mi][r], off));
    if (c == 0)
#pragma unroll
        for (int mi = 0; mi < 4; ++mi)
#pragma unroll
            for (int r = 0; r < 4; ++r) red[(mi * 16 + q * 4 + r) * 12 + w] = mx[mi][r];
    __syncthreads();
#pragma unroll
    for (int mi = 0; mi < 4; ++mi)
#pragma unroll
        for (int r = 0; r < 4; ++r) {
            const float* rp = red + (mi * 16 + q * 4 + r) * 12;
            mx[mi][r] = fmaxf(fmaxf(rp[0], rp[1]), fmaxf(rp[2], rp[3]));
        }
    float suml[4][4], sumw[4][4];
#pragma unroll
    for (int mi = 0; mi < 4; ++mi)
#pragma unroll
        for (int r = 0; r < 4; ++r) { suml[mi][r] = 0.f; sumw[mi][r] = 0.f; }
#pragma unroll
    for (int mi = 0; mi < 4; ++mi)
#pragma unroll
        for (int ni = 0; ni < 4; ++ni) {
            const int n = w * 64 + ni * 16 + c;
            const float wov = swo[n];
#pragma unroll
            for (int r = 0; r < 4; ++r) {
                int m = mi * 16 + q * 4 + r;
                float e = __expf(acc[mi][ni][r] - mx[mi][r]);
                suml[mi][r] += e;
                sumw[mi][r] += e * bf2f(sA[m * 264 + n]) * wov;
            }
        }
#pragma unroll
    for (int off = 1; off < 16; off <<= 1)
#pragma unroll
        for (int mi = 0; mi < 4; ++mi)
#pragma unroll
            for (int r = 0; r < 4; ++r) {
                suml[mi][r] += __shfl_xor(suml[mi][r], off);
                sumw[mi][r] += __shfl_xor(sumw[mi][r], off);
            }
    __syncthreads();
    if (c == 0)
#pragma unroll
        for (int mi = 0; mi < 4; ++mi)
#pragma unroll
            for (int r = 0; r < 4; ++r) {
                int m = mi * 16 + q * 4 + r;
                red[m * 12 + 4 + w] = suml[mi][r];
                red[m * 12 + 8 + w] = sumw[mi][r];
            }
    __syncthreads();
    if (tid < 64) {
        const float* rp = red + tid * 12;
        float lsum = rp[4] + rp[5] + rp[6] + rp[7];
        float wsum = rp[8] + rp[9] + rp[10] + rp[11];
        out[row0 + tid] = wsum / lsum + bo[0];
    }
}

extern "C" void kernel_launch(void* const* d_in, const int* in_sizes, int n_in,
                              void* d_out, int out_size, void* d_ws, size_t ws_size,
                              hipStream_t stream) {
    const float* x    = (const float*)d_in[0];
    const float* Wih1 = (const float*)d_in[1];
    const float* bih1 = (const float*)d_in[2];
    const float* Whh1 = (const float*)d_in[3];
    const float* bhh1 = (const float*)d_in[4];
    const float* Wih2 = (const float*)d_in[5];
    const float* bih2 = (const float*)d_in[6];
    const float* Whh2 = (const float*)d_in[7];
    const float* bhh2 = (const float*)d_in[8];
    const float* Wa1  = (const float*)d_in[9];
    const float* ba1  = (const float*)d_in[10];
    const float* Wa2  = (const float*)d_in[11];
    const float* ba2  = (const float*)d_in[12];
    const float* Wo   = (const float*)d_in[13];
    const float* bo   = (const float*)d_in[14];

    char* ws = (char*)d_ws;
    u16*   Wa1b  = (u16*)(ws + 0);                  // 128 KB
    u16*   Wa2b  = (u16*)(ws + 131072);             // 128 KB
    float* bias1 = (float*)(ws + 262144);           // 4 KB
    float* bias2 = (float*)(ws + 266240);           // 4 KB
    u32*   flags = (u32*)(ws + 270336);             // 16 KB (128 x 128B slots)
    u32*   Hb1   = (u32*)(ws + 524288);             // 512 KB [2][256][256] u32
    u32*   Hb2   = (u32*)(ws + 1048576);            // 512 KB
    u16*   H2    = (u16*)(ws + 2097152);            // 64 MB
    float* out   = (float*)d_out;

    (void)hipMemsetAsync(flags, 0, 16384, stream);
    bias_kernel<<<4, 256, 0, stream>>>(bih1, bhh1, bih2, bhh2, bias1, bias2);
    cvt_bf_kernel<<<256, 256, 0, stream>>>(Wa1, Wa1b, 65536);
    cvt_bf_kernel<<<256, 256, 0, stream>>>(Wa2, Wa2b, 65536);

    lstm_persist<<<128, 512, 0, stream>>>(x, Wih1, bias1, bias2,
                                          Whh1, Wih2, Whh2, Hb1, Hb2, H2, flags);
    attn_fused<<<2048, 256, 0, stream>>>(Wa1b, Wa2b, ba1, ba2, Wo, bo, H2, out);
}